// Round 1
// baseline (2762.706 us; speedup 1.0000x reference)
//
#include <hip/hip_runtime.h>
#include <hip/hip_bf16.h>
#include <cstdint>

#define AS1 __attribute__((address_space(1)))
#define AS3 __attribute__((address_space(3)))

typedef unsigned short u16;
typedef unsigned int u32;
typedef __bf16 bf16_t;
typedef bf16_t bf16x8 __attribute__((ext_vector_type(8)));
typedef float f32x4 __attribute__((ext_vector_type(4)));

static constexpr int M = 8192;     // 2*4096 tokens
static constexpr int N = 16384;    // output features
static constexpr int K = 4096;     // input features
static constexpr int BM = 128, BN = 128, BK = 32;
static constexpr long long W_ELEMS = (long long)N * K;  // 67108864
static constexpr long long X_ELEMS = (long long)M * K;  // 33554432

__device__ __forceinline__ u16 f32_to_bf16_rne(float f) {
    u32 u = __float_as_uint(f);
    u += 0x7fffu + ((u >> 16) & 1u);
    return (u16)(u >> 16);
}

// ---------------- mean(|w|) reduction: f64 partials + f64 atomic ----------------
__global__ void wabs_sum_kernel(const float* __restrict__ w, double* __restrict__ out) {
    __shared__ double sred[256];
    const float4* w4 = (const float4*)w;
    const int n4 = (int)(W_ELEMS / 4);
    double s = 0.0;
    for (int i = blockIdx.x * blockDim.x + threadIdx.x; i < n4; i += gridDim.x * blockDim.x) {
        float4 v = w4[i];
        s += (double)fabsf(v.x) + (double)fabsf(v.y) + (double)fabsf(v.z) + (double)fabsf(v.w);
    }
    sred[threadIdx.x] = s;
    __syncthreads();
    for (int off = 128; off > 0; off >>= 1) {
        if ((int)threadIdx.x < off) sred[threadIdx.x] += sred[threadIdx.x + off];
        __syncthreads();
    }
    if (threadIdx.x == 0) atomicAdd(out, sred[0]);
}

// ---------------- ternary quantize w -> bf16 {-1,0,1} ----------------
__global__ void w_quant_kernel(const float4* __restrict__ w4, const double* __restrict__ wsum,
                               ushort4* __restrict__ wq) {
    const double scale = fmax(wsum[0] * (1.0 / 67108864.0), 1e-5);
    const double inv = 1.0 / scale;
    const int n4 = (int)(W_ELEMS / 4);
    for (int i = blockIdx.x * blockDim.x + threadIdx.x; i < n4; i += gridDim.x * blockDim.x) {
        float4 v = w4[i];
        float q0 = fminf(fmaxf((float)rint((double)v.x * inv), -1.f), 1.f);
        float q1 = fminf(fmaxf((float)rint((double)v.y * inv), -1.f), 1.f);
        float q2 = fminf(fmaxf((float)rint((double)v.z * inv), -1.f), 1.f);
        float q3 = fminf(fmaxf((float)rint((double)v.w * inv), -1.f), 1.f);
        ushort4 o;
        o.x = f32_to_bf16_rne(q0);
        o.y = f32_to_bf16_rne(q1);
        o.z = f32_to_bf16_rne(q2);
        o.w = f32_to_bf16_rne(q3);
        wq[i] = o;
    }
}

// ---------------- x fp32 -> bf16 (RNE) ----------------
__global__ void x_conv_kernel(const float4* __restrict__ x4, ushort4* __restrict__ xb) {
    const int n4 = (int)(X_ELEMS / 4);
    for (int i = blockIdx.x * blockDim.x + threadIdx.x; i < n4; i += gridDim.x * blockDim.x) {
        float4 v = x4[i];
        ushort4 o;
        o.x = f32_to_bf16_rne(v.x);
        o.y = f32_to_bf16_rne(v.y);
        o.z = f32_to_bf16_rne(v.z);
        o.w = f32_to_bf16_rne(v.w);
        xb[i] = o;
    }
}

// ---------------- async global->LDS, 16B per lane ----------------
__device__ __forceinline__ void gld16(const void* gptr, const void* lptr) {
    __builtin_amdgcn_global_load_lds(
        (AS1 u32*)(uintptr_t)gptr,
        (AS3 u32*)(u32)(uintptr_t)lptr,
        16, 0, 0);
}

// ---------------- GEMM: C[M,N] = A[M,K](bf16) * B[N,K](bf16)^T, fp32 out ----------------
// m97-style: 128x128 tile, BK=32, 4 waves, 4x4 16x16x32 MFMAs per wave.
__global__ __launch_bounds__(256) void gemm_bt_kernel(const u16* __restrict__ A,
                                                      const u16* __restrict__ B,
                                                      float* __restrict__ C) {
    __shared__ __align__(16) u16 sA[BM * BK];   // [row][k] row-major, 8 KiB
    __shared__ __align__(16) u16 sB[BN * BK];   // [row][k] row-major, 8 KiB

    const int tid = threadIdx.x;
    const int wid = tid >> 6;
    const int lane = tid & 63;

    // band swizzle: GM=4 m-tiles per band, m-fastest within band (L2 locality)
    constexpr int GM = 4;
    constexpr int NT = N / BN;  // 128
    const int bid = blockIdx.x;
    const int band = bid / (GM * NT);
    const int r0 = bid % (GM * NT);
    const int m0 = (band * GM + (r0 % GM)) * BM;
    const int n0 = (r0 / GM) * BN;

    // staging: thread t loads 16B at row=t/4, colblock=t%4 (8 bf16)
    const int srow = tid >> 2;
    const int scb = tid & 3;
    const u16* gA0 = A + (size_t)(m0 + srow) * K + scb * 8;
    const u16* gA1 = gA0 + (size_t)64 * K;
    const u16* gB0 = B + (size_t)(n0 + srow) * K + scb * 8;
    const u16* gB1 = gB0 + (size_t)64 * K;
    // wave-uniform LDS bases: lds byte = inst*4096 + wid*1024 + lane*16
    const u16* lA0 = &sA[wid * 512];
    const u16* lA1 = &sA[2048 + wid * 512];
    const u16* lB0 = &sB[wid * 512];
    const u16* lB1 = &sB[2048 + wid * 512];

    const int wm = (wid & 1) * 64;
    const int wn = (wid >> 1) * 64;
    const int fr = lane & 15;   // frag row (A m / B n / C col)
    const int fq = lane >> 4;   // quad

    f32x4 acc[4][4] = {};

    for (int k0 = 0; k0 < K; k0 += BK) {
        __syncthreads();  // previous compute done before LDS overwrite
        gld16(gA0 + k0, lA0);
        gld16(gA1 + k0, lA1);
        gld16(gB0 + k0, lB0);
        gld16(gB1 + k0, lB1);
        __syncthreads();  // compiler emits vmcnt(0) drain before barrier

        bf16x8 a[4], b[4];
#pragma unroll
        for (int mt = 0; mt < 4; ++mt)
            a[mt] = *(const bf16x8*)&sA[(wm + mt * 16 + fr) * BK + fq * 8];
#pragma unroll
        for (int nt = 0; nt < 4; ++nt)
            b[nt] = *(const bf16x8*)&sB[(wn + nt * 16 + fr) * BK + fq * 8];
#pragma unroll
        for (int mt = 0; mt < 4; ++mt)
#pragma unroll
            for (int nt = 0; nt < 4; ++nt)
                acc[mt][nt] = __builtin_amdgcn_mfma_f32_16x16x32_bf16(a[mt], b[nt], acc[mt][nt], 0, 0, 0);
    }

    // epilogue: C/D layout col=lane&15, row=(lane>>4)*4+reg
#pragma unroll
    for (int mt = 0; mt < 4; ++mt) {
#pragma unroll
        for (int i = 0; i < 4; ++i) {
            const size_t rrow = (size_t)(m0 + wm + mt * 16 + fq * 4 + i);
            float* Crow = C + rrow * N + n0 + wn + fr;
#pragma unroll
            for (int nt = 0; nt < 4; ++nt)
                Crow[nt * 16] = acc[mt][nt][i];
        }
    }
}

extern "C" void kernel_launch(void* const* d_in, const int* in_sizes, int n_in,
                              void* d_out, int out_size, void* d_ws, size_t ws_size,
                              hipStream_t stream) {
    const float* x = (const float*)d_in[0];
    const float* w = (const float*)d_in[1];
    float* out = (float*)d_out;

    char* ws = (char*)d_ws;
    double* wsum = (double*)ws;                                   // 8 B accumulator
    u16* wq = (u16*)(ws + 256);                                   // 128 MiB bf16 w_q
    u16* xb = (u16*)(ws + 256 + (size_t)W_ELEMS * 2);             // 64 MiB bf16 x

    hipMemsetAsync(wsum, 0, 64, stream);
    wabs_sum_kernel<<<1024, 256, 0, stream>>>(w, wsum);
    w_quant_kernel<<<4096, 256, 0, stream>>>((const float4*)w, wsum, (ushort4*)wq);
    x_conv_kernel<<<2048, 256, 0, stream>>>((const float4*)x, (ushort4*)xb);

    const int nblocks = (M / BM) * (N / BN);  // 8192
    gemm_bt_kernel<<<nblocks, 256, 0, stream>>>(xb, wq, out);
}